// Round 16
// baseline (245.419 us; speedup 1.0000x reference)
//
#include <hip/hip_runtime.h>
#include <stdint.h>

typedef unsigned short ushort_t;
typedef __attribute__((__ext_vector_type__(8))) __bf16 bf16x8;
typedef __attribute__((__ext_vector_type__(4))) float f32x4;

__device__ inline ushort_t f2bf(float f) {
    unsigned int u = __float_as_uint(f);
    u = u + 0x7FFFu + ((u >> 16) & 1u);
    return (ushort_t)(u >> 16);
}
__device__ inline float bf2f(ushort_t h) {
    return __uint_as_float(((unsigned int)h) << 16);
}

#define GLOAD16(gp, lp) __builtin_amdgcn_global_load_lds( \
    (__attribute__((address_space(1))) void*)(gp),        \
    (__attribute__((address_space(3))) void*)(lp), 16, 0, 0)

// =====================================================================
// NT GEMM: C[M,N] = A[M,K] * B[N,K]^T  (A,B bf16-as-ushort)
// Configs: {BM=128, NTHR=256, 4 waves 2x2} (r11-r15 proven) and
//          {BM=256, NTHR=512, 8 waves 2x4} (same skeleton, bigger tile:
//          halves staged-bytes/output; 128KB LDS dbuf, 1 blk/CU, 8 waves).
// Wave tile: (BM/2) x 64. MI=BM/32 row-frags, NR=4 col-frags.
// T3 minimum-2-phase loop (proven): static 4-buffer dbuf, unroll-by-2,
// full-drain barrier per K-tile. T2 granule swizzle: s(row)=row&7 (GPR=8);
// LDS slot g holds global granule g^s(row); read f uses f^s(row).
// XCD-chunked block swizzle (grids multiples of 8).
// MODE 0: C bf16 (+opt bias) | MODE 3: C f32 + bias
// MODE 4: QKV split epilogue | MODE 5: C = exp(v*scale) bf16 (no atomics)
// =====================================================================
template<int MODE, int BM, int BN, int BK, int NTHR>
__global__ __launch_bounds__(NTHR, 2)
void gemm_nt(const ushort_t* __restrict__ A, const ushort_t* __restrict__ B,
             void* __restrict__ Cv, const float* __restrict__ bias,
             int K, int lda, int ldb, int ldc, float scale,
             long long sA, long long sB, long long sC)
{
    constexpr int WC  = NTHR / 128;      // wave-cols: 2 (256thr) or 4 (512thr)
    constexpr int WN  = BN / WC;         // 64 in both configs
    constexpr int NR  = WN / 16;         // 4
    constexpr int MI  = (BM / 2) / 16;   // 4 or 8
    constexpr int GPR = BK / 8;          // 8 for BK=64
    constexpr int AG  = BM * GPR;
    constexpr int BG  = BN * GPR;
    constexpr int ABYTES = BM * BK * 2;
    constexpr int BBYTES = BN * BK * 2;
    __shared__ __align__(16) char lds[2 * (ABYTES + BBYTES)];
    char* const ldsA0 = lds;
    char* const ldsB0 = lds + ABYTES;
    char* const ldsA1 = lds + ABYTES + BBYTES;
    char* const ldsB1 = lds + 2 * ABYTES + BBYTES;

    const int t = threadIdx.x;

    // ---- XCD-chunked swizzle ----
    const int gx = gridDim.x, gy = gridDim.y;
    const int nwg = gx * gy * gridDim.z;
    int h = (blockIdx.z * gy + blockIdx.y) * gx + blockIdx.x;
    int logical = (h & 7) * (nwg >> 3) + (h >> 3);
    const int bx = logical % gx;
    const int tmp = logical / gx;
    const int by = tmp % gy;
    const int z  = tmp / gy;

    A += (size_t)z * (size_t)sA;
    B += (size_t)z * (size_t)sB;

    const int rowBase = by * BM;
    const int colBase = bx * BN;

    const int w    = t >> 6;
    const int lane = t & 63;
    const int wr = w / WC, wc = w % WC;
    const int lr = lane & 15, lg = lane >> 4;

    auto swz = [](int row) -> int {
        return (GPR == 8) ? (row & 7) : ((row >> 1) & 3);
    };

    f32x4 acc[MI][NR];
#pragma unroll
    for (int i = 0; i < MI; ++i)
#pragma unroll
        for (int j = 0; j < NR; ++j)
            acc[i][j] = (f32x4){0.f, 0.f, 0.f, 0.f};

    auto stage = [&](int kt, char* dA, char* dB) {
#pragma unroll
        for (int i = 0; i < AG / NTHR; ++i) {
            const int L = i * NTHR + t;
            const int row = L / GPR, g = L % GPR;
            const int gs = g ^ swz(row);
            GLOAD16(A + (size_t)(rowBase + row) * (size_t)lda + (kt + gs * 8),
                    dA + L * 16);
        }
#pragma unroll
        for (int i = 0; i < BG / NTHR; ++i) {
            const int L = i * NTHR + t;
            const int row = L / GPR, g = L % GPR;
            const int gs = g ^ swz(row);
            GLOAD16(B + (size_t)(colBase + row) * (size_t)ldb + (kt + gs * 8),
                    dB + L * 16);
        }
    };
    auto mfma_phase = [&](const char* la, const char* lb) {
        const bf16x8* A8 = (const bf16x8*)la;
        const bf16x8* B8 = (const bf16x8*)lb;
#pragma unroll
        for (int kk = 0; kk < BK / 32; ++kk) {
            bf16x8 af[MI], bq[NR];
#pragma unroll
            for (int mi = 0; mi < MI; ++mi) {
                const int ar = wr * (BM / 2) + mi * 16 + lr;
                af[mi] = A8[ar * GPR + ((kk * 4 + lg) ^ swz(ar))];
            }
#pragma unroll
            for (int ni = 0; ni < NR; ++ni) {
                const int br = wc * WN + ni * 16 + lr;
                bq[ni] = B8[br * GPR + ((kk * 4 + lg) ^ swz(br))];
            }
#pragma unroll
            for (int mi = 0; mi < MI; ++mi)
#pragma unroll
                for (int ni = 0; ni < NR; ++ni)
                    acc[mi][ni] = __builtin_amdgcn_mfma_f32_16x16x32_bf16(
                        af[mi], bq[ni], acc[mi][ni], 0, 0, 0);
        }
    };

    const int NT = K / BK;               // even for all K used (8 or 32)
    stage(0, ldsA0, ldsB0);
    __syncthreads();
    for (int it = 0; it < NT; it += 2) {
        stage((it + 1) * BK, ldsA1, ldsB1);
        mfma_phase(ldsA0, ldsB0);
        __syncthreads();
        if (it + 2 < NT) stage((it + 2) * BK, ldsA0, ldsB0);
        mfma_phase(ldsA1, ldsB1);
        __syncthreads();
    }

    // ---- epilogue ----
#pragma unroll
    for (int mi = 0; mi < MI; ++mi) {
#pragma unroll
        for (int ni = 0; ni < NR; ++ni) {
#pragma unroll
            for (int r = 0; r < 4; ++r) {
                const int grow = rowBase + wr * (BM / 2) + mi * 16 + lg * 4 + r;
                const int gcol = colBase + wc * WN + ni * 16 + lr;
                float v = acc[mi][ni][r] * scale;
                if (MODE == 0) {
                    if (bias) v += bias[gcol];
                    ushort_t* C = (ushort_t*)Cv + (size_t)z * (size_t)sC;
                    C[(size_t)grow * (size_t)ldc + gcol] = f2bf(v);
                } else if (MODE == 3) {
                    float* C = (float*)Cv;
                    C[(size_t)grow * (size_t)ldc + gcol] = v + bias[gcol];
                } else if (MODE == 4) {
                    v += bias[gcol];
                    const int seg = gcol >> 9, c = gcol & 511;
                    ushort_t* C = (ushort_t*)Cv;
                    C[(size_t)seg * 8388608 + (size_t)grow * 512 + c] = f2bf(v);
                } else { // MODE 5
                    ushort_t* C = (ushort_t*)Cv + (size_t)z * (size_t)sC;
                    C[(size_t)grow * (size_t)ldc + gcol] = f2bf(__expf(v));
                }
            }
        }
    }
}

// =====================================================================
// V [8][2048][512] -> Vt [8][512][2048]
// =====================================================================
__global__ __launch_bounds__(256)
void transpose_v(const ushort_t* __restrict__ V, ushort_t* __restrict__ Vt)
{
    __shared__ ushort_t lds[64][68];
    const int t = threadIdx.x;
    const int nBase = blockIdx.x * 64;
    const int dBase = blockIdx.y * 64;
    const size_t b = blockIdx.z;
    const ushort_t* src = V + b * 1048576;
    ushort_t* dst = Vt + b * 1048576;
#pragma unroll
    for (int i = 0; i < 2; ++i) {
        int s = i * 256 + t;
        int n = s >> 3, dg = s & 7;
        union { ushort_t h[8]; uint4 u; } p;
        p.u = *(const uint4*)(src + (size_t)(nBase + n) * 512 + dBase + dg * 8);
#pragma unroll
        for (int j = 0; j < 8; ++j) lds[n][dg * 8 + j] = p.h[j];
    }
    __syncthreads();
#pragma unroll
    for (int i = 0; i < 2; ++i) {
        int s = i * 256 + t;
        int d = s >> 3, ng = s & 7;
        union { ushort_t h[8]; uint4 u; } p;
#pragma unroll
        for (int j = 0; j < 8; ++j) p.h[j] = lds[ng * 8 + j][d];
        *(uint4*)(dst + (size_t)(dBase + d) * 2048 + nBase + ng * 8) = p.u;
    }
}

// =====================================================================
// One-shot prologue: convert X (2097152 float4 granules), 4 weight
// matrices (4x65536 granules) and pack 3 bias vectors.
// Grid: 8192 (X) + 1024 (W) + 6 (bias+tail) = 9222 blocks x 256.
// =====================================================================
__global__ __launch_bounds__(256)
void prologue(const float* __restrict__ X, ushort_t* __restrict__ Xb,
              const float* __restrict__ wq, const float* __restrict__ wk,
              const float* __restrict__ wv, const float* __restrict__ wo,
              ushort_t* __restrict__ Wqkv, ushort_t* __restrict__ Wob2,
              const float* __restrict__ bq, const float* __restrict__ bk,
              const float* __restrict__ bv, float* __restrict__ biasP)
{
    const int i = blockIdx.x * 256 + threadIdx.x;
    if (i < 2097152) {                               // X convert
        float4 v = ((const float4*)X)[i];
        union { ushort_t h[4]; uint2 u; } p;
        p.h[0] = f2bf(v.x); p.h[1] = f2bf(v.y);
        p.h[2] = f2bf(v.z); p.h[3] = f2bf(v.w);
        ((uint2*)Xb)[i] = p.u;
    } else if (i < 2097152 + 262144) {               // weights convert
        const int k = i - 2097152;
        const int seg = k >> 16, j = k & 65535;
        const float* src = (seg == 0) ? wq : (seg == 1) ? wk
                         : (seg == 2) ? wv : wo;
        ushort_t* dst = (seg == 3) ? Wob2 : (Wqkv + seg * 262144);
        float4 v = ((const float4*)src)[j];
        union { ushort_t h[4]; uint2 u; } p;
        p.h[0] = f2bf(v.x); p.h[1] = f2bf(v.y);
        p.h[2] = f2bf(v.z); p.h[3] = f2bf(v.w);
        ((uint2*)dst)[j] = p.u;
    } else {                                         // bias pack
        const int j = i - 2097152 - 262144;
        if (j < 512) biasP[j] = bq[j];
        else if (j < 1024) biasP[j] = bk[j - 512];
        else if (j < 1536) biasP[j] = bv[j - 1024];
    }
}

// =====================================================================
// attn = E/rowsum + intensity, bf16 in-place over E. One block per row.
// =====================================================================
__global__ __launch_bounds__(256)
void norm_add(ushort_t* __restrict__ E, const float* __restrict__ inten)
{
    const int R = blockIdx.x;
    const int t = threadIdx.x;
    const int w = t >> 6, lane = t & 63;
    ushort_t* erow = E + (size_t)R * 2048;
    const float* irow = inten + (size_t)R * 2048;

    union { ushort_t h[8]; uint4 u; } p;
    p.u = *(const uint4*)(erow + t * 8);
    float f[8];
#pragma unroll
    for (int j = 0; j < 8; ++j) f[j] = bf2f(p.h[j]);

    float s = 0.f;
#pragma unroll
    for (int j = 0; j < 8; ++j) s += f[j];
#pragma unroll
    for (int off = 32; off > 0; off >>= 1) s += __shfl_xor(s, off);

    __shared__ float red[4];
    if (lane == 0) red[w] = s;
    __syncthreads();
    const float inv = 1.f / (red[0] + red[1] + red[2] + red[3]);

    float4 i0 = *(const float4*)(irow + t * 8);
    float4 i1 = *(const float4*)(irow + t * 8 + 4);
    float o[8] = { f[0]*inv + i0.x, f[1]*inv + i0.y, f[2]*inv + i0.z, f[3]*inv + i0.w,
                   f[4]*inv + i1.x, f[5]*inv + i1.y, f[6]*inv + i1.z, f[7]*inv + i1.w };
#pragma unroll
    for (int j = 0; j < 8; ++j) p.h[j] = f2bf(o[j]);
    *(uint4*)(erow + t * 8) = p.u;
}

// =====================================================================
extern "C" void kernel_launch(void* const* d_in, const int* in_sizes, int n_in,
                              void* d_out, int out_size, void* d_ws, size_t ws_size,
                              hipStream_t stream)
{
    const float* X    = (const float*)d_in[0];
    const float* inten= (const float*)d_in[1];
    const float* WQw  = (const float*)d_in[2];
    const float* WQb  = (const float*)d_in[3];
    const float* WKw  = (const float*)d_in[4];
    const float* WKb  = (const float*)d_in[5];
    const float* WVw  = (const float*)d_in[6];
    const float* WVb  = (const float*)d_in[7];
    const float* Wow  = (const float*)d_in[8];
    const float* Wob  = (const float*)d_in[9];
    float* out = (float*)d_out;

    char* ws = (char*)d_ws;
    ushort_t* Vt    = (ushort_t*)(ws + 0);           // 16 MiB
    ushort_t* Wqkv  = (ushort_t*)(ws + 16777216);    // 1536x512 bf16
    ushort_t* Wob2  = (ushort_t*)(ws + 18350080);    // 512x512 bf16
    float*    biasP = (float*)   (ws + 18874368);    // 1536 f32
    ushort_t* QKV   = (ushort_t*)(ws + 19922944);    // Q|K|V row-major, 3x16 MiB
    ushort_t* out1  = (ushort_t*)(ws + 70254592);    // 16 MiB
    ushort_t* Sbf   = (ushort_t*)(ws + 87031808);    // E bf16, 64 MiB
    ushort_t* Xb    = (ushort_t*)(ws + 154140672);   // 16 MiB
    ushort_t* Qb  = QKV;
    ushort_t* Kb  = QKV + 8388608;
    ushort_t* Vrm = QKV + 16777216;

    const float scale = 0.044194173824159216f;       // 1/sqrt(512)

    prologue<<<dim3(9222), dim3(256), 0, stream>>>(
        X, Xb, WQw, WKw, WVw, Wow, Wqkv, Wob2, WQb, WKb, WVb, biasP);

    // fused QKV projection: [16384,512] @ [1536,512]^T, 256^2 tile
    gemm_nt<4, 256, 256, 64, 512><<<dim3(6, 64, 1), dim3(512), 0, stream>>>(
        Xb, Wqkv, QKV, biasP, 512, 512, 512, 0, 1.f, 0, 0, 0);

    // Vt[b][d][n] = V[b][n][d]
    transpose_v<<<dim3(32, 8, 8), dim3(256), 0, stream>>>(Vrm, Vt);

    // E = exp(scale * Q K^T) bf16, per batch, 256^2 tile
    gemm_nt<5, 256, 256, 64, 512><<<dim3(8, 8, 8), dim3(512), 0, stream>>>(
        Qb, Kb, Sbf, nullptr, 512, 512, 512, 2048, scale,
        2048LL * 512, 2048LL * 512, 2048LL * 2048);

    // attn = E/rowsum + intensity (bf16, in place, self-reducing)
    norm_add<<<dim3(16384), dim3(256), 0, stream>>>(Sbf, inten);

    // out1 = attn @ Vt^T per batch  [2048,512] bf16  (128^2 tile)
    gemm_nt<0, 128, 128, 64, 256><<<dim3(4, 16, 8), dim3(256), 0, stream>>>(
        Sbf, Vt, out1, nullptr, 2048, 2048, 2048, 512, 1.f,
        2048LL * 2048, 512LL * 2048, 2048LL * 512);

    // out = out1 @ Wo^T + bo  [16384,512] f32  (128^2 tile)
    gemm_nt<3, 128, 128, 64, 256><<<dim3(4, 128, 1), dim3(256), 0, stream>>>(
        out1, Wob2, out, Wob, 512, 512, 512, 512, 1.f, 0, 0, 0);
}

// Round 17
// 200.095 us; speedup vs baseline: 1.2265x; 1.2265x over previous
//
#include <hip/hip_runtime.h>
#include <stdint.h>

typedef unsigned short ushort_t;
typedef __attribute__((__ext_vector_type__(8))) __bf16 bf16x8;
typedef __attribute__((__ext_vector_type__(4))) float f32x4;

__device__ inline ushort_t f2bf(float f) {
    unsigned int u = __float_as_uint(f);
    u = u + 0x7FFFu + ((u >> 16) & 1u);
    return (ushort_t)(u >> 16);
}
__device__ inline float bf2f(ushort_t h) {
    return __uint_as_float(((unsigned int)h) << 16);
}

#define GLOAD16(gp, lp) __builtin_amdgcn_global_load_lds( \
    (__attribute__((address_space(1))) void*)(gp),        \
    (__attribute__((address_space(3))) void*)(lp), 16, 0, 0)

// =====================================================================
// NT GEMM: C[M,N] = A[M,K] * B[N,K]^T  (A,B bf16-as-ushort)
// BM=128, BN=128, BK=64 (r15-proven best config): 64KB LDS dbuf ->
// 2 blocks/CU. NOTE (r16 lesson): the 2-phase full-drain barrier REQUIRES
// >=2 blocks/CU so the other block's waves cover the drain; 256^2 tiles
// (1 blk/CU) stall the whole CU at every barrier and regress 50%.
// 256 thr = 4 waves (2x2), wave tile 64x64.
// T3 minimum-2-phase loop (r11-r15 proven): static 4-buffer dbuf.
// T2 granule swizzle (rule 21): GPR=8: s(row)=row&7; LDS slot g holds
// global granule g^s(row); fragment read f uses slot f^s(row).
// XCD-chunked block swizzle (grids multiples of 8).
// MODE 0: C bf16 (+opt bias) | MODE 3: C f32 + bias
// MODE 4: QKV split epilogue | MODE 5: C = exp(v*scale) bf16 (no atomics)
// =====================================================================
template<int MODE, int BN, int BK>
__global__ __launch_bounds__(256)
void gemm_nt(const ushort_t* __restrict__ A, const ushort_t* __restrict__ B,
             void* __restrict__ Cv, const float* __restrict__ bias,
             int K, int lda, int ldb, int ldc, float scale,
             long long sA, long long sB, long long sC)
{
    constexpr int WN  = BN / 2;
    constexpr int NR  = WN / 16;
    constexpr int GPR = BK / 8;          // 8 for BK=64
    constexpr int AG  = 128 * GPR;
    constexpr int BG  = BN * GPR;
    constexpr int ABYTES = 128 * BK * 2;
    constexpr int BBYTES = BN * BK * 2;
    __shared__ __align__(16) char lds[2 * (ABYTES + BBYTES)];
    char* const ldsA0 = lds;
    char* const ldsB0 = lds + ABYTES;
    char* const ldsA1 = lds + ABYTES + BBYTES;
    char* const ldsB1 = lds + 2 * ABYTES + BBYTES;

    const int t = threadIdx.x;

    // ---- XCD-chunked swizzle ----
    const int gx = gridDim.x, gy = gridDim.y;
    const int nwg = gx * gy * gridDim.z;
    int h = (blockIdx.z * gy + blockIdx.y) * gx + blockIdx.x;
    int logical = (h & 7) * (nwg >> 3) + (h >> 3);
    const int bx = logical % gx;
    const int tmp = logical / gx;
    const int by = tmp % gy;
    const int z  = tmp / gy;

    A += (size_t)z * (size_t)sA;
    B += (size_t)z * (size_t)sB;

    const int rowBase = by * 128;
    const int colBase = bx * BN;

    const int w    = t >> 6;
    const int lane = t & 63;
    const int wr = w >> 1, wc = w & 1;
    const int lr = lane & 15, lg = lane >> 4;

    auto swz = [](int row) -> int {
        return (GPR == 8) ? (row & 7) : ((row >> 1) & 3);
    };

    f32x4 acc[4][NR];
#pragma unroll
    for (int i = 0; i < 4; ++i)
#pragma unroll
        for (int j = 0; j < NR; ++j)
            acc[i][j] = (f32x4){0.f, 0.f, 0.f, 0.f};

    auto stage = [&](int kt, char* dA, char* dB) {
#pragma unroll
        for (int i = 0; i < AG / 256; ++i) {
            const int L = i * 256 + t;
            const int row = L / GPR, g = L % GPR;
            const int gs = g ^ swz(row);
            GLOAD16(A + (size_t)(rowBase + row) * (size_t)lda + (kt + gs * 8),
                    dA + L * 16);
        }
#pragma unroll
        for (int i = 0; i < BG / 256; ++i) {
            const int L = i * 256 + t;
            const int row = L / GPR, g = L % GPR;
            const int gs = g ^ swz(row);
            GLOAD16(B + (size_t)(colBase + row) * (size_t)ldb + (kt + gs * 8),
                    dB + L * 16);
        }
    };
    auto mfma_phase = [&](const char* la, const char* lb) {
        const bf16x8* A8 = (const bf16x8*)la;
        const bf16x8* B8 = (const bf16x8*)lb;
#pragma unroll
        for (int kk = 0; kk < BK / 32; ++kk) {
            bf16x8 af[4], bq[NR];
#pragma unroll
            for (int mi = 0; mi < 4; ++mi) {
                const int ar = wr * 64 + mi * 16 + lr;
                af[mi] = A8[ar * GPR + ((kk * 4 + lg) ^ swz(ar))];
            }
#pragma unroll
            for (int ni = 0; ni < NR; ++ni) {
                const int br = wc * WN + ni * 16 + lr;
                bq[ni] = B8[br * GPR + ((kk * 4 + lg) ^ swz(br))];
            }
#pragma unroll
            for (int mi = 0; mi < 4; ++mi)
#pragma unroll
                for (int ni = 0; ni < NR; ++ni)
                    acc[mi][ni] = __builtin_amdgcn_mfma_f32_16x16x32_bf16(
                        af[mi], bq[ni], acc[mi][ni], 0, 0, 0);
        }
    };

    const int NT = K / BK;               // even for all K used (8 or 32)
    stage(0, ldsA0, ldsB0);
    __syncthreads();
    for (int it = 0; it < NT; it += 2) {
        stage((it + 1) * BK, ldsA1, ldsB1);
        mfma_phase(ldsA0, ldsB0);
        __syncthreads();
        if (it + 2 < NT) stage((it + 2) * BK, ldsA0, ldsB0);
        mfma_phase(ldsA1, ldsB1);
        __syncthreads();
    }

    // ---- epilogue ----
#pragma unroll
    for (int mi = 0; mi < 4; ++mi) {
#pragma unroll
        for (int ni = 0; ni < NR; ++ni) {
#pragma unroll
            for (int r = 0; r < 4; ++r) {
                const int grow = rowBase + wr * 64 + mi * 16 + lg * 4 + r;
                const int gcol = colBase + wc * WN + ni * 16 + lr;
                float v = acc[mi][ni][r] * scale;
                if (MODE == 0) {
                    if (bias) v += bias[gcol];
                    ushort_t* C = (ushort_t*)Cv + (size_t)z * (size_t)sC;
                    C[(size_t)grow * (size_t)ldc + gcol] = f2bf(v);
                } else if (MODE == 3) {
                    float* C = (float*)Cv;
                    C[(size_t)grow * (size_t)ldc + gcol] = v + bias[gcol];
                } else if (MODE == 4) {
                    v += bias[gcol];
                    const int seg = gcol >> 9, c = gcol & 511;
                    ushort_t* C = (ushort_t*)Cv;
                    C[(size_t)seg * 8388608 + (size_t)grow * 512 + c] = f2bf(v);
                } else { // MODE 5
                    ushort_t* C = (ushort_t*)Cv + (size_t)z * (size_t)sC;
                    C[(size_t)grow * (size_t)ldc + gcol] = f2bf(__expf(v));
                }
            }
        }
    }
}

// =====================================================================
// V [8][2048][512] -> Vt [8][512][2048]
// =====================================================================
__global__ __launch_bounds__(256)
void transpose_v(const ushort_t* __restrict__ V, ushort_t* __restrict__ Vt)
{
    __shared__ ushort_t lds[64][68];
    const int t = threadIdx.x;
    const int nBase = blockIdx.x * 64;
    const int dBase = blockIdx.y * 64;
    const size_t b = blockIdx.z;
    const ushort_t* src = V + b * 1048576;
    ushort_t* dst = Vt + b * 1048576;
#pragma unroll
    for (int i = 0; i < 2; ++i) {
        int s = i * 256 + t;
        int n = s >> 3, dg = s & 7;
        union { ushort_t h[8]; uint4 u; } p;
        p.u = *(const uint4*)(src + (size_t)(nBase + n) * 512 + dBase + dg * 8);
#pragma unroll
        for (int j = 0; j < 8; ++j) lds[n][dg * 8 + j] = p.h[j];
    }
    __syncthreads();
#pragma unroll
    for (int i = 0; i < 2; ++i) {
        int s = i * 256 + t;
        int d = s >> 3, ng = s & 7;
        union { ushort_t h[8]; uint4 u; } p;
#pragma unroll
        for (int j = 0; j < 8; ++j) p.h[j] = lds[ng * 8 + j][d];
        *(uint4*)(dst + (size_t)(dBase + d) * 2048 + nBase + ng * 8) = p.u;
    }
}

// =====================================================================
__global__ __launch_bounds__(256)
void cvt_bf16(const float* __restrict__ src, ushort_t* __restrict__ dst, int n4)
{
    int i = blockIdx.x * 256 + threadIdx.x;
    if (i >= n4) return;
    float4 v = ((const float4*)src)[i];
    union { ushort_t h[4]; uint2 u; } p;
    p.h[0] = f2bf(v.x); p.h[1] = f2bf(v.y); p.h[2] = f2bf(v.z); p.h[3] = f2bf(v.w);
    ((uint2*)dst)[i] = p.u;
}

// =====================================================================
// One-shot prologue: convert 4 weight matrices and pack 3 bias vectors.
// =====================================================================
__global__ __launch_bounds__(256)
void prep_weights(const float* __restrict__ wq, const float* __restrict__ wk,
                  const float* __restrict__ wv, const float* __restrict__ wo,
                  ushort_t* __restrict__ Wqkv, ushort_t* __restrict__ Wob2,
                  const float* __restrict__ bq, const float* __restrict__ bk,
                  const float* __restrict__ bv, float* __restrict__ biasP)
{
    const int i = blockIdx.x * 256 + threadIdx.x;
    if (i < 262144) {
        const int seg = i >> 16, j = i & 65535;
        const float* src = (seg == 0) ? wq : (seg == 1) ? wk
                         : (seg == 2) ? wv : wo;
        ushort_t* dst = (seg == 3) ? Wob2 : (Wqkv + seg * 262144);
        float4 v = ((const float4*)src)[j];
        union { ushort_t h[4]; uint2 u; } p;
        p.h[0] = f2bf(v.x); p.h[1] = f2bf(v.y);
        p.h[2] = f2bf(v.z); p.h[3] = f2bf(v.w);
        ((uint2*)dst)[j] = p.u;
    } else {
        const int j = i - 262144;
        if (j < 512) biasP[j] = bq[j];
        else if (j < 1024) biasP[j] = bk[j - 512];
        else if (j < 1536) biasP[j] = bv[j - 1024];
    }
}

// =====================================================================
// attn = E/rowsum + intensity, bf16 in-place over E. One block per row.
// =====================================================================
__global__ __launch_bounds__(256)
void norm_add(ushort_t* __restrict__ E, const float* __restrict__ inten)
{
    const int R = blockIdx.x;
    const int t = threadIdx.x;
    const int w = t >> 6, lane = t & 63;
    ushort_t* erow = E + (size_t)R * 2048;
    const float* irow = inten + (size_t)R * 2048;

    union { ushort_t h[8]; uint4 u; } p;
    p.u = *(const uint4*)(erow + t * 8);
    float f[8];
#pragma unroll
    for (int j = 0; j < 8; ++j) f[j] = bf2f(p.h[j]);

    float s = 0.f;
#pragma unroll
    for (int j = 0; j < 8; ++j) s += f[j];
#pragma unroll
    for (int off = 32; off > 0; off >>= 1) s += __shfl_xor(s, off);

    __shared__ float red[4];
    if (lane == 0) red[w] = s;
    __syncthreads();
    const float inv = 1.f / (red[0] + red[1] + red[2] + red[3]);

    float4 i0 = *(const float4*)(irow + t * 8);
    float4 i1 = *(const float4*)(irow + t * 8 + 4);
    float o[8] = { f[0]*inv + i0.x, f[1]*inv + i0.y, f[2]*inv + i0.z, f[3]*inv + i0.w,
                   f[4]*inv + i1.x, f[5]*inv + i1.y, f[6]*inv + i1.z, f[7]*inv + i1.w };
#pragma unroll
    for (int j = 0; j < 8; ++j) p.h[j] = f2bf(o[j]);
    *(uint4*)(erow + t * 8) = p.u;
}

// =====================================================================
extern "C" void kernel_launch(void* const* d_in, const int* in_sizes, int n_in,
                              void* d_out, int out_size, void* d_ws, size_t ws_size,
                              hipStream_t stream)
{
    const float* X    = (const float*)d_in[0];
    const float* inten= (const float*)d_in[1];
    const float* WQw  = (const float*)d_in[2];
    const float* WQb  = (const float*)d_in[3];
    const float* WKw  = (const float*)d_in[4];
    const float* WKb  = (const float*)d_in[5];
    const float* WVw  = (const float*)d_in[6];
    const float* WVb  = (const float*)d_in[7];
    const float* Wow  = (const float*)d_in[8];
    const float* Wob  = (const float*)d_in[9];
    float* out = (float*)d_out;

    char* ws = (char*)d_ws;
    ushort_t* Vt    = (ushort_t*)(ws + 0);           // 16 MiB
    ushort_t* Wqkv  = (ushort_t*)(ws + 16777216);    // 1536x512 bf16
    ushort_t* Wob2  = (ushort_t*)(ws + 18350080);    // 512x512 bf16
    float*    biasP = (float*)   (ws + 18874368);    // 1536 f32
    ushort_t* QKV   = (ushort_t*)(ws + 19922944);    // Q|K|V row-major, 3x16 MiB
    ushort_t* out1  = (ushort_t*)(ws + 70254592);    // 16 MiB
    ushort_t* Sbf   = (ushort_t*)(ws + 87031808);    // E bf16, 64 MiB
    ushort_t* Xb    = (ushort_t*)(ws + 154140672);   // 16 MiB
    ushort_t* Qb  = QKV;
    ushort_t* Kb  = QKV + 8388608;
    ushort_t* Vrm = QKV + 16777216;

    const float scale = 0.044194173824159216f;       // 1/sqrt(512)

    cvt_bf16<<<dim3(8192), dim3(256), 0, stream>>>(X, Xb, 2097152);
    prep_weights<<<dim3(1030), dim3(256), 0, stream>>>(
        WQw, WKw, WVw, Wow, Wqkv, Wob2, WQb, WKb, WVb, biasP);

    // fused QKV projection: [16384,512] @ [1536,512]^T -> Q|K|V row-major
    gemm_nt<4, 128, 64><<<dim3(12, 128, 1), dim3(256), 0, stream>>>(
        Xb, Wqkv, QKV, biasP, 512, 512, 512, 0, 1.f, 0, 0, 0);

    // Vt[b][d][n] = V[b][n][d]
    transpose_v<<<dim3(32, 8, 8), dim3(256), 0, stream>>>(Vrm, Vt);

    // E = exp(scale * Q K^T) bf16, per batch
    gemm_nt<5, 128, 64><<<dim3(16, 16, 8), dim3(256), 0, stream>>>(
        Qb, Kb, Sbf, nullptr, 512, 512, 512, 2048, scale,
        2048LL * 512, 2048LL * 512, 2048LL * 2048);

    // attn = E/rowsum + intensity (bf16, in place, self-reducing)
    norm_add<<<dim3(16384), dim3(256), 0, stream>>>(Sbf, inten);

    // out1 = attn @ Vt^T per batch  [2048,512] bf16
    gemm_nt<0, 128, 64><<<dim3(4, 16, 8), dim3(256), 0, stream>>>(
        Sbf, Vt, out1, nullptr, 2048, 2048, 2048, 512, 1.f,
        2048LL * 2048, 512LL * 2048, 2048LL * 512);

    // out = out1 @ Wo^T + bo  [16384,512] f32
    gemm_nt<3, 128, 64><<<dim3(4, 128, 1), dim3(256), 0, stream>>>(
        out1, Wob2, out, Wob, 512, 512, 512, 512, 1.f, 0, 0, 0);
}